// Round 7
// baseline (177.809 us; speedup 1.0000x reference)
//
#include <hip/hip_runtime.h>

typedef _Float16 half8 __attribute__((ext_vector_type(8)));
typedef _Float16 half4 __attribute__((ext_vector_type(4)));
typedef float    f32x4 __attribute__((ext_vector_type(4)));
typedef unsigned long long u64;

#define B_ 16
#define C_ 256
#define N_ 4096
#define TAU 0.02f

// swizzled f16 index into X[k][n32][i256]: XOR spreads n-rows across 16B bank-columns.
// (n>>1)&7 gives 8 distinct columns on the (even-n) write side AND the read side -> 2-way max.
#define SWZ16(k, n, i) (((((k) * 32 + (n)) * 256) + (i)) ^ ((((n) >> 1) & 7) << 3))

__device__ __forceinline__ u64 shfl_xor_u64(u64 v, int m) {
    unsigned lo = __shfl_xor((unsigned)v, m);
    unsigned hi = __shfl_xor((unsigned)(v >> 32), m);
    return ((u64)hi << 32) | lo;
}
// merge top-2 B into A (packed keys: higher = better; ~n low 32 gives first-index tie rule)
__device__ __forceinline__ void t2m(u64& A1, u64& A2, u64 B1, u64 B2) {
    bool aw = A1 > B1;
    u64 T1 = aw ? A1 : B1;
    u64 lv = aw ? B1 : A1;
    u64 wv = aw ? A2 : B2;
    A2 = lv > wv ? lv : wv;
    A1 = T1;
}
__device__ __forceinline__ float unkey(unsigned key) {
    unsigned u = (key & 0x80000000u) ? (key ^ 0x80000000u) : ~key;
    return __uint_as_float(u);
}

// ---------- prep: W' = 16*W -> f16 hi/lo, A-fragment-major ----------
__global__ void prep_w(const float* __restrict__ W,
                       _Float16* __restrict__ WfH, _Float16* __restrict__ WfL) {
    int t = blockIdx.x * 256 + threadIdx.x;  // 0..8191
    int l = t & 63, g = t >> 6;
    int s = g & 7, cb = g >> 3;
    int c = cb * 16 + (l & 15);
    int i0 = s * 32 + (l >> 4) * 8;
    int base = ((cb * 8 + s) * 64 + l) * 8;
#pragma unroll
    for (int j = 0; j < 8; ++j) {
        float w = 16.0f * W[c * C_ + i0 + j];
        _Float16 h  = (_Float16)w;
        _Float16 lo = (_Float16)(w - (float)h);
        WfH[base + j] = h;
        WfL[base + j] = lo;
    }
}

// ---------- main: whole-K-resident LDS, one barrier, 2-pass f16 MFMA ----------
// grid: 16 b * 128 n-windows (32 n); 512 thr = 8 waves = 4 cw (64 c) x 2 nw (16 n)
// launch_bounds(512,6): 3 blocks/CU (144 KB LDS), VGPR cap 85 >= used.
__global__ __launch_bounds__(512, 6) void vn_main(
    const float* __restrict__ x,
    const _Float16* __restrict__ WfH, const _Float16* __restrict__ WfL,
    ulonglong2* __restrict__ btop)
{
    __shared__ __align__(16) _Float16 X[3 * 32 * 256];   // 48 KB, swizzled [k][n][i]

    const int tid  = threadIdx.x;
    const int lane = tid & 63;
    const int wid  = tid >> 6;
    const int nw   = wid & 1;
    const int cw   = wid >> 1;
    const int b    = blockIdx.x >> 7;
    const int nb   = blockIdx.x & 127;
    const int n0   = nb << 5;
    const int g    = lane >> 4;
    const int t16  = lane & 15;

    const float* xb = x + ((size_t)(b * 768) << 12);

    // ---- stage all of x[b, :, :, n0:n0+32] -> LDS f16 (one burst, rolling 2-deep) ----
    const int npair = tid & 15;
    const int rg    = tid >> 4;    // 0..31
    float2 vb[2][4];

#define LOADP(P, PR)                                                              \
    do { int rgp = (P) * 32 + rg; int i4 = rgp / 3, kk = rgp - 3 * i4;            \
        _Pragma("unroll") for (int rr = 0; rr < 4; ++rr)                          \
            vb[PR][rr] = *(const float2*)(xb +                                    \
                (((i4 * 4 + rr) * 3 + kk) << 12) + n0 + 2 * npair);               \
    } while (0)

#define WRITEP(P, PR)                                                             \
    do { int rgp = (P) * 32 + rg; int i4 = rgp / 3, kk = rgp - 3 * i4;            \
        _Pragma("unroll") for (int nn = 0; nn < 2; ++nn) {                        \
            int n = 2 * npair + nn;                                               \
            half4 h;                                                              \
            h[0] = (_Float16)(nn ? vb[PR][0].y : vb[PR][0].x);                    \
            h[1] = (_Float16)(nn ? vb[PR][1].y : vb[PR][1].x);                    \
            h[2] = (_Float16)(nn ? vb[PR][2].y : vb[PR][2].x);                    \
            h[3] = (_Float16)(nn ? vb[PR][3].y : vb[PR][3].x);                    \
            *(half4*)(&X[SWZ16(kk, n, i4 * 4)]) = h;                              \
        } } while (0)

    LOADP(0, 0);
#pragma unroll
    for (int p = 0; p < 6; ++p) {
        if (p < 5) LOADP(p + 1, (p + 1) & 1);
        WRITEP(p, p & 1);
    }
    __syncthreads();     // the ONLY barrier: X is read-only from here on

    // ---- MFMA: d = W'@x_hi, W split hi+lo (2 passes), K fully resident ----
    f32x4 acc[3][4];
    const f32x4 zero = {0.f, 0.f, 0.f, 0.f};
#pragma unroll
    for (int k = 0; k < 3; ++k)
#pragma unroll
        for (int cf = 0; cf < 4; ++cf) acc[k][cf] = zero;

    half8 ah[4], al[4];

#pragma unroll
    for (int s = 0; s < 8; ++s) {
#pragma unroll
        for (int cf = 0; cf < 4; ++cf) {
            int off = (((((cw << 2) + cf) << 3) + s) * 64 + lane) << 3;
            ah[cf] = *(const half8*)(WfH + off);
            al[cf] = *(const half8*)(WfL + off);
        }
        half8 bh[3];
#pragma unroll
        for (int k = 0; k < 3; ++k)
            bh[k] = *(const half8*)(&X[SWZ16(k, (nw << 4) | t16, (s << 5) + (g << 3))]);
#pragma unroll
        for (int k = 0; k < 3; ++k)
#pragma unroll
            for (int cf = 0; cf < 4; ++cf)
                acc[k][cf] = __builtin_amdgcn_mfma_f32_16x16x32_f16(ah[cf], bh[k], acc[k][cf], 0, 0, 0);
#pragma unroll
        for (int k = 0; k < 3; ++k)
#pragma unroll
            for (int cf = 0; cf < 4; ++cf)
                acc[k][cf] = __builtin_amdgcn_mfma_f32_16x16x32_f16(al[cf], bh[k], acc[k][cf], 0, 0, 0);
    }

    // ---- epilogue: dp from LDS x, pack key, 16-lane top-2, one store per (c, window) ----
#pragma unroll
    for (int cf = 0; cf < 4; ++cf) {
        half4 xr[3];
#pragma unroll
        for (int k = 0; k < 3; ++k)
            xr[k] = *(const half4*)(&X[SWZ16(k, (nw << 4) | t16, (cw << 6) + (cf << 4) + (g << 2))]);
#pragma unroll
        for (int r = 0; r < 4; ++r) {
            float dp = 0.f;
#pragma unroll
            for (int k = 0; k < 3; ++k)
                dp += (float)xr[k][r] * acc[k][cf][r];
            dp *= 0.0625f;
            unsigned u = __float_as_uint(dp);
            unsigned key = (u & 0x80000000u) ? ~u : (u | 0x80000000u);
            int n = n0 + (nw << 4) + t16;
            u64 A1 = ((u64)key << 32) | (unsigned)(~n);
            u64 A2 = 0;
#pragma unroll
            for (int m = 1; m <= 8; m <<= 1) {
                u64 B1 = shfl_xor_u64(A1, m);
                u64 B2 = shfl_xor_u64(A2, m);
                t2m(A1, A2, B1, B2);
            }
            if (t16 == 0) {
                int c = (cw << 6) + (cf << 4) + (g << 2) + r;
                btop[(size_t)((b << 8) + c) * 256 + (nb << 1) + nw] = make_ulonglong2(A1, A2);
            }
        }
    }
}

// ---------- phase2: merge 256 windows, certify or exact-recompute, gather ----------
__global__ void phase2(const float* __restrict__ x, const float* __restrict__ W,
                       const ulonglong2* __restrict__ btop, float* __restrict__ out)
{
    const int bc = blockIdx.x;
    const int b = bc >> 8, c = bc & 255;
    const int lane = threadIdx.x;

    u64 A1 = 0, A2 = 0;
    u64 e1[4];
#pragma unroll
    for (int t = 0; t < 4; ++t) {
        ulonglong2 e = btop[(size_t)bc * 256 + t * 64 + lane];
        e1[t] = e.x;
        t2m(A1, A2, e.x, e.y);
    }
#pragma unroll
    for (int m = 1; m <= 32; m <<= 1) {
        u64 B1 = shfl_xor_u64(A1, m);
        u64 B2 = shfl_xor_u64(A2, m);
        t2m(A1, A2, B1, B2);
    }
    float v1 = unkey((unsigned)(A1 >> 32));
    float v2 = unkey((unsigned)(A2 >> 32));
    int winner = (int)(~(unsigned)A1) & (N_ - 1);

    if (!(v1 - v2 > TAU)) {
        float bv = -3.4e38f; int bi = 0x7fffffff;
#pragma unroll
        for (int t = 0; t < 4; ++t) {
            bool flag = unkey((unsigned)(e1[t] >> 32)) >= v1 - TAU;
            unsigned long long mask = __ballot(flag);
            while (mask) {
                int src = __builtin_ctzll(mask);
                mask &= mask - 1;
                int win = t * 64 + src;
                for (int ch = 0; ch < 2; ++ch) {
                    int nbase = win * 16 + ch * 8;
                    float accv[8];
#pragma unroll
                    for (int m2 = 0; m2 < 8; ++m2) accv[m2] = 0.f;
                    float xc[3][8];
#pragma unroll
                    for (int k = 0; k < 3; ++k) {
                        const float* p = x + (((size_t)bc * 3 + k) << 12) + nbase;
#pragma unroll
                        for (int m2 = 0; m2 < 8; ++m2) xc[k][m2] = p[m2];
                    }
                    for (int q = 0; q < 4; ++q) {
                        int i = lane + (q << 6);
                        float wq = W[c * C_ + i];
#pragma unroll
                        for (int k = 0; k < 3; ++k) {
                            const float* p = x + ((((size_t)b * C_ + i) * 3 + k) << 12) + nbase;
#pragma unroll
                            for (int m2 = 0; m2 < 8; ++m2)
                                accv[m2] += wq * p[m2] * xc[k][m2];
                        }
                    }
#pragma unroll
                    for (int m2 = 0; m2 < 8; ++m2) {
#pragma unroll
                        for (int mm = 1; mm <= 32; mm <<= 1)
                            accv[m2] += __shfl_xor(accv[m2], mm);
                        int n = nbase + m2;
                        if (accv[m2] > bv || (accv[m2] == bv && n < bi)) { bv = accv[m2]; bi = n; }
                    }
                }
            }
        }
        winner = bi;
    }

    if (lane < 3)
        out[bc * 3 + lane] = x[(((size_t)bc * 3 + lane) << 12) + winner];
}

extern "C" void kernel_launch(void* const* d_in, const int* in_sizes, int n_in,
                              void* d_out, int out_size, void* d_ws, size_t ws_size,
                              hipStream_t stream) {
    const float* x = (const float*)d_in[0];
    const float* W = (const float*)d_in[1];
    float* out = (float*)d_out;

    _Float16*   WfH  = (_Float16*)d_ws;                      // 128 KB
    _Float16*   WfL  = (_Float16*)((char*)d_ws + 131072);    // 128 KB
    ulonglong2* btop = (ulonglong2*)((char*)d_ws + 262144);  // 16 MB: [bc][256] (K1,K2)

    prep_w<<<32, 256, 0, stream>>>(W, WfH, WfL);
    vn_main<<<B_ * 128, 512, 0, stream>>>(x, WfH, WfL, btop);
    phase2<<<B_ * C_, 64, 0, stream>>>(x, W, btop, out);
}

// Round 8
// 118.438 us; speedup vs baseline: 1.5013x; 1.5013x over previous
//
#include <hip/hip_runtime.h>

typedef _Float16 half8 __attribute__((ext_vector_type(8)));
typedef _Float16 half4 __attribute__((ext_vector_type(4)));
typedef float    f32x4 __attribute__((ext_vector_type(4)));
typedef unsigned long long u64;

#define B_ 16
#define C_ 256
#define N_ 4096
#define TAU 0.02f

// swizzled f16 index into X[k][n32][i256]: XOR spreads n-rows across 16B bank-columns.
#define SWZ16(k, n, i) (((((k) * 32 + (n)) * 256) + (i)) ^ ((((n) >> 1) & 7) << 3))

__device__ __forceinline__ u64 shfl_xor_u64(u64 v, int m) {
    unsigned lo = __shfl_xor((unsigned)v, m);
    unsigned hi = __shfl_xor((unsigned)(v >> 32), m);
    return ((u64)hi << 32) | lo;
}
// merge top-2 B into A (packed keys: higher = better; ~n low 32 gives first-index tie rule)
__device__ __forceinline__ void t2m(u64& A1, u64& A2, u64 B1, u64 B2) {
    bool aw = A1 > B1;
    u64 T1 = aw ? A1 : B1;
    u64 lv = aw ? B1 : A1;
    u64 wv = aw ? A2 : B2;
    A2 = lv > wv ? lv : wv;
    A1 = T1;
}
__device__ __forceinline__ float unkey(unsigned key) {
    unsigned u = (key & 0x80000000u) ? (key ^ 0x80000000u) : ~key;
    return __uint_as_float(u);
}

// ---------- prep: W' = 16*W -> f16 hi/lo, A-fragment-major ----------
// f16 index: ((cb*8+s)*64 + l)*8 + j ;  c = cb*16+(l&15), i = s*32+(l>>4)*8+j
__global__ void prep_w(const float* __restrict__ W,
                       _Float16* __restrict__ WfH, _Float16* __restrict__ WfL) {
    int t = blockIdx.x * 256 + threadIdx.x;  // 0..8191
    int l = t & 63, g = t >> 6;
    int s = g & 7, cb = g >> 3;
    int c = cb * 16 + (l & 15);
    int i0 = s * 32 + (l >> 4) * 8;
    int base = ((cb * 8 + s) * 64 + l) * 8;
#pragma unroll
    for (int j = 0; j < 8; ++j) {
        float w = 16.0f * W[c * C_ + i0 + j];
        _Float16 h  = (_Float16)w;
        _Float16 lo = (_Float16)(w - (float)h);
        WfH[base + j] = h;
        WfL[base + j] = lo;
    }
}

// ---------- main: whole-K-resident LDS, one barrier, 2-pass f16 MFMA ----------
// grid: 16 b * 128 n-windows (32 n); 512 thr = 8 waves; wave w owns c[32w,32w+32), all 32 n.
// No W duplication across waves; ah ping-pong + al reuse pipelines the L2 W loads.
__global__ __launch_bounds__(512, 4) void vn_main(
    const float* __restrict__ x,
    const _Float16* __restrict__ WfH, const _Float16* __restrict__ WfL,
    ulonglong2* __restrict__ btop)
{
    __shared__ __align__(16) _Float16 X[3 * 32 * 256];   // 48 KB, swizzled [k][n][i]

    const int tid  = threadIdx.x;
    const int lane = tid & 63;
    const int wid  = tid >> 6;      // 0..7 : c-slice
    const int b    = blockIdx.x >> 7;
    const int nb   = blockIdx.x & 127;
    const int n0   = nb << 5;
    const int g    = lane >> 4;
    const int t16  = lane & 15;

    const float* xb = x + ((size_t)(b * 768) << 12);

    // ---- stage all of x[b, :, :, n0:n0+32] -> LDS f16 (one burst, rolling 2-deep) ----
    const int npair = tid & 15;
    const int rg    = tid >> 4;    // 0..31
    float2 vb[2][4];

#define LOADP(P, PR)                                                              \
    do { int rgp = (P) * 32 + rg; int i4 = rgp / 3, kk = rgp - 3 * i4;            \
        _Pragma("unroll") for (int rr = 0; rr < 4; ++rr)                          \
            vb[PR][rr] = *(const float2*)(xb +                                    \
                (((i4 * 4 + rr) * 3 + kk) << 12) + n0 + 2 * npair);               \
    } while (0)

#define WRITEP(P, PR)                                                             \
    do { int rgp = (P) * 32 + rg; int i4 = rgp / 3, kk = rgp - 3 * i4;            \
        _Pragma("unroll") for (int nn = 0; nn < 2; ++nn) {                        \
            int n = 2 * npair + nn;                                               \
            half4 h;                                                              \
            h[0] = (_Float16)(nn ? vb[PR][0].y : vb[PR][0].x);                    \
            h[1] = (_Float16)(nn ? vb[PR][1].y : vb[PR][1].x);                    \
            h[2] = (_Float16)(nn ? vb[PR][2].y : vb[PR][2].x);                    \
            h[3] = (_Float16)(nn ? vb[PR][3].y : vb[PR][3].x);                    \
            *(half4*)(&X[SWZ16(kk, n, i4 * 4)]) = h;                              \
        } } while (0)

    LOADP(0, 0);
#pragma unroll
    for (int p = 0; p < 6; ++p) {
        if (p < 5) LOADP(p + 1, (p + 1) & 1);
        WRITEP(p, p & 1);
    }
    __syncthreads();     // the ONLY barrier: X is read-only from here on

    // ---- MFMA: d = W'@x_hi, W split hi+lo (2 passes), K fully resident ----
    f32x4 acc[3][2][2];  // [k][cf][nf]
    const f32x4 zero = {0.f, 0.f, 0.f, 0.f};
#pragma unroll
    for (int k = 0; k < 3; ++k)
#pragma unroll
        for (int cf = 0; cf < 2; ++cf)
#pragma unroll
            for (int nf = 0; nf < 2; ++nf) acc[k][cf][nf] = zero;

    half8 ah[2][2], al[2];   // ah ping-pong [parity][cf]; al single-buffer [cf]

#define WOFF(CF, S) ((((((wid << 1) + (CF)) << 3) + (S)) * 64 + lane) << 3)

    // prologue: slice-0 W frags
#pragma unroll
    for (int cf = 0; cf < 2; ++cf) {
        ah[0][cf] = *(const half8*)(WfH + WOFF(cf, 0));
        al[cf]    = *(const half8*)(WfL + WOFF(cf, 0));
    }

#pragma unroll
    for (int s = 0; s < 8; ++s) {
        const int P = s & 1;
        // B-frags for this slice (LDS)
        half8 bh[3][2];
#pragma unroll
        for (int k = 0; k < 3; ++k)
#pragma unroll
            for (int nf = 0; nf < 2; ++nf)
                bh[k][nf] = *(const half8*)(&X[SWZ16(k, (nf << 4) | t16, (s << 5) + (g << 3))]);
        // prefetch next slice's hi frags (cover = this slice's hi+lo passes)
        if (s < 7)
#pragma unroll
            for (int cf = 0; cf < 2; ++cf)
                ah[P ^ 1][cf] = *(const half8*)(WfH + WOFF(cf, s + 1));
        // hi pass
#pragma unroll
        for (int k = 0; k < 3; ++k)
#pragma unroll
            for (int cf = 0; cf < 2; ++cf)
#pragma unroll
                for (int nf = 0; nf < 2; ++nf)
                    acc[k][cf][nf] = __builtin_amdgcn_mfma_f32_16x16x32_f16(ah[P][cf], bh[k][nf], acc[k][cf][nf], 0, 0, 0);
        // lo pass
#pragma unroll
        for (int k = 0; k < 3; ++k)
#pragma unroll
            for (int cf = 0; cf < 2; ++cf)
#pragma unroll
                for (int nf = 0; nf < 2; ++nf)
                    acc[k][cf][nf] = __builtin_amdgcn_mfma_f32_16x16x32_f16(al[cf], bh[k][nf], acc[k][cf][nf], 0, 0, 0);
        // al now dead: issue next slice's lo frags (cover = next slice's hi pass)
        if (s < 7)
#pragma unroll
            for (int cf = 0; cf < 2; ++cf)
                al[cf] = *(const half8*)(WfL + WOFF(cf, s + 1));
    }

    // ---- epilogue: dp from LDS x, pack keys, merge both n-halves per 32-n window ----
#pragma unroll
    for (int cf = 0; cf < 2; ++cf) {
        half4 xrA[3], xrB[3];
        const int ci = (wid << 5) + (cf << 4) + (g << 2);
#pragma unroll
        for (int k = 0; k < 3; ++k) {
            xrA[k] = *(const half4*)(&X[SWZ16(k, t16,      ci)]);
            xrB[k] = *(const half4*)(&X[SWZ16(k, 16 | t16, ci)]);
        }
#pragma unroll
        for (int r = 0; r < 4; ++r) {
            float dpA = 0.f, dpB = 0.f;
#pragma unroll
            for (int k = 0; k < 3; ++k) {
                dpA += (float)xrA[k][r] * acc[k][cf][0][r];
                dpB += (float)xrB[k][r] * acc[k][cf][1][r];
            }
            dpA *= 0.0625f; dpB *= 0.0625f;
            unsigned uA = __float_as_uint(dpA);
            unsigned keyA = (uA & 0x80000000u) ? ~uA : (uA | 0x80000000u);
            unsigned uB = __float_as_uint(dpB);
            unsigned keyB = (uB & 0x80000000u) ? ~uB : (uB | 0x80000000u);
            int nA = n0 + t16, nB = n0 + 16 + t16;
            u64 A1 = ((u64)keyA << 32) | (unsigned)(~nA);
            u64 A2 = 0;
            u64 B1 = ((u64)keyB << 32) | (unsigned)(~nB);
            t2m(A1, A2, B1, 0);
#pragma unroll
            for (int m = 1; m <= 8; m <<= 1) {
                u64 C1 = shfl_xor_u64(A1, m);
                u64 C2 = shfl_xor_u64(A2, m);
                t2m(A1, A2, C1, C2);
            }
            if (t16 == 0) {
                int c = ci + r;
                btop[(size_t)((b << 8) + c) * 128 + nb] = make_ulonglong2(A1, A2);
            }
        }
    }
}

// ---------- phase2: merge 128 windows, certify or exact-recompute, gather ----------
__global__ void phase2(const float* __restrict__ x, const float* __restrict__ W,
                       const ulonglong2* __restrict__ btop, float* __restrict__ out)
{
    const int bc = blockIdx.x;
    const int b = bc >> 8, c = bc & 255;
    const int lane = threadIdx.x;

    u64 A1 = 0, A2 = 0;
    u64 e1[2];
#pragma unroll
    for (int t = 0; t < 2; ++t) {
        ulonglong2 e = btop[(size_t)bc * 128 + t * 64 + lane];
        e1[t] = e.x;
        t2m(A1, A2, e.x, e.y);
    }
#pragma unroll
    for (int m = 1; m <= 32; m <<= 1) {
        u64 B1 = shfl_xor_u64(A1, m);
        u64 B2 = shfl_xor_u64(A2, m);
        t2m(A1, A2, B1, B2);
    }
    float v1 = unkey((unsigned)(A1 >> 32));
    float v2 = unkey((unsigned)(A2 >> 32));
    int winner = (int)(~(unsigned)A1) & (N_ - 1);

    if (!(v1 - v2 > TAU)) {
        float bv = -3.4e38f; int bi = 0x7fffffff;
#pragma unroll
        for (int t = 0; t < 2; ++t) {
            bool flag = unkey((unsigned)(e1[t] >> 32)) >= v1 - TAU;
            unsigned long long mask = __ballot(flag);
            while (mask) {
                int src = __builtin_ctzll(mask);
                mask &= mask - 1;
                int win = t * 64 + src;       // 32-n window
                for (int ch = 0; ch < 4; ++ch) {
                    int nbase = win * 32 + ch * 8;
                    float accv[8];
#pragma unroll
                    for (int m2 = 0; m2 < 8; ++m2) accv[m2] = 0.f;
                    float xc[3][8];
#pragma unroll
                    for (int k = 0; k < 3; ++k) {
                        const float* p = x + (((size_t)bc * 3 + k) << 12) + nbase;
#pragma unroll
                        for (int m2 = 0; m2 < 8; ++m2) xc[k][m2] = p[m2];
                    }
                    for (int q = 0; q < 4; ++q) {
                        int i = lane + (q << 6);
                        float wq = W[c * C_ + i];
#pragma unroll
                        for (int k = 0; k < 3; ++k) {
                            const float* p = x + ((((size_t)b * C_ + i) * 3 + k) << 12) + nbase;
#pragma unroll
                            for (int m2 = 0; m2 < 8; ++m2)
                                accv[m2] += wq * p[m2] * xc[k][m2];
                        }
                    }
#pragma unroll
                    for (int m2 = 0; m2 < 8; ++m2) {
#pragma unroll
                        for (int mm = 1; mm <= 32; mm <<= 1)
                            accv[m2] += __shfl_xor(accv[m2], mm);
                        int n = nbase + m2;
                        if (accv[m2] > bv || (accv[m2] == bv && n < bi)) { bv = accv[m2]; bi = n; }
                    }
                }
            }
        }
        winner = bi;
    }

    if (lane < 3)
        out[bc * 3 + lane] = x[(((size_t)bc * 3 + lane) << 12) + winner];
}

extern "C" void kernel_launch(void* const* d_in, const int* in_sizes, int n_in,
                              void* d_out, int out_size, void* d_ws, size_t ws_size,
                              hipStream_t stream) {
    const float* x = (const float*)d_in[0];
    const float* W = (const float*)d_in[1];
    float* out = (float*)d_out;

    _Float16*   WfH  = (_Float16*)d_ws;                      // 128 KB
    _Float16*   WfL  = (_Float16*)((char*)d_ws + 131072);    // 128 KB
    ulonglong2* btop = (ulonglong2*)((char*)d_ws + 262144);  // 8 MB: [bc][128] (K1,K2)

    prep_w<<<32, 256, 0, stream>>>(W, WfH, WfL);
    vn_main<<<B_ * 128, 512, 0, stream>>>(x, WfH, WfL, btop);
    phase2<<<B_ * C_, 64, 0, stream>>>(x, W, btop, out);
}

// Round 9
// 116.683 us; speedup vs baseline: 1.5239x; 1.0150x over previous
//
#include <hip/hip_runtime.h>

typedef _Float16 half8 __attribute__((ext_vector_type(8)));
typedef _Float16 half4 __attribute__((ext_vector_type(4)));
typedef float    f32x4 __attribute__((ext_vector_type(4)));
typedef unsigned long long u64;

#define B_ 16
#define C_ 256
#define N_ 4096
#define TAU 0.02f

// swizzled f16 index into X[k][n32][i256]: XOR spreads n-rows across 16B bank-columns.
#define SWZ16(k, n, i) (((((k) * 32 + (n)) * 256) + (i)) ^ ((((n) >> 1) & 7) << 3))

__device__ __forceinline__ u64 shfl_xor_u64(u64 v, int m) {
    unsigned lo = __shfl_xor((unsigned)v, m);
    unsigned hi = __shfl_xor((unsigned)(v >> 32), m);
    return ((u64)hi << 32) | lo;
}
// merge top-2 B into A (packed keys: higher = better; ~n low 32 gives first-index tie rule)
__device__ __forceinline__ void t2m(u64& A1, u64& A2, u64 B1, u64 B2) {
    bool aw = A1 > B1;
    u64 T1 = aw ? A1 : B1;
    u64 lv = aw ? B1 : A1;
    u64 wv = aw ? A2 : B2;
    A2 = lv > wv ? lv : wv;
    A1 = T1;
}
__device__ __forceinline__ float unkey(unsigned key) {
    unsigned u = (key & 0x80000000u) ? (key ^ 0x80000000u) : ~key;
    return __uint_as_float(u);
}

// ---------- prep: W' = 16*W -> f16 hi/lo, A-fragment-major ----------
// f16 index: ((cb*8+s)*64 + l)*8 + j ;  c = cb*16+(l&15), i = s*32+(l>>4)*8+j
__global__ void prep_w(const float* __restrict__ W,
                       _Float16* __restrict__ WfH, _Float16* __restrict__ WfL) {
    int t = blockIdx.x * 256 + threadIdx.x;  // 0..8191
    int l = t & 63, g = t >> 6;
    int s = g & 7, cb = g >> 3;
    int c = cb * 16 + (l & 15);
    int i0 = s * 32 + (l >> 4) * 8;
    int base = ((cb * 8 + s) * 64 + l) * 8;
#pragma unroll
    for (int j = 0; j < 8; ++j) {
        float w = 16.0f * W[c * C_ + i0 + j];
        _Float16 h  = (_Float16)w;
        _Float16 lo = (_Float16)(w - (float)h);
        WfH[base + j] = h;
        WfL[base + j] = lo;
    }
}

// ---------- main: whole-K-resident LDS, one barrier, 2-pass f16 MFMA ----------
// grid: 16 b * 128 n-windows (32 n); 512 thr = 8 waves; wave w owns c[32w,32w+32), all 32 n.
// Depth-3 stage pipeline keeps 12 global loads in flight; W slice-0 prefetched pre-stage.
__global__ __launch_bounds__(512, 4) void vn_main(
    const float* __restrict__ x,
    const _Float16* __restrict__ WfH, const _Float16* __restrict__ WfL,
    ulonglong2* __restrict__ btop)
{
    __shared__ __align__(16) _Float16 X[3 * 32 * 256];   // 48 KB, swizzled [k][n][i]

    const int tid  = threadIdx.x;
    const int lane = tid & 63;
    const int wid  = tid >> 6;      // 0..7 : c-slice
    const int b    = blockIdx.x >> 7;
    const int nb   = blockIdx.x & 127;
    const int n0   = nb << 5;
    const int g    = lane >> 4;
    const int t16  = lane & 15;

    const float* xb = x + ((size_t)(b * 768) << 12);

    half8 ah[2][2], al[2];   // ah ping-pong [parity][cf]; al single-buffer [cf]
#define WOFF(CF, S) ((((((wid << 1) + (CF)) << 3) + (S)) * 64 + lane) << 3)

    // W slice-0 frags: issue FIRST (L2-resident; fully covered by the stage phase)
#pragma unroll
    for (int cf = 0; cf < 2; ++cf) {
        ah[0][cf] = *(const half8*)(WfH + WOFF(cf, 0));
        al[cf]    = *(const half8*)(WfL + WOFF(cf, 0));
    }

    // ---- stage all of x[b, :, :, n0:n0+32] -> LDS f16 (depth-3 rolling pipeline) ----
    const int npair = tid & 15;
    const int rg    = tid >> 4;    // 0..31
    float2 vb[3][4];

#define LOADP(P, PR)                                                              \
    do { int rgp = (P) * 32 + rg; int i4 = rgp / 3, kk = rgp - 3 * i4;            \
        _Pragma("unroll") for (int rr = 0; rr < 4; ++rr)                          \
            vb[PR][rr] = *(const float2*)(xb +                                    \
                (((i4 * 4 + rr) * 3 + kk) << 12) + n0 + 2 * npair);               \
    } while (0)

#define WRITEP(P, PR)                                                             \
    do { int rgp = (P) * 32 + rg; int i4 = rgp / 3, kk = rgp - 3 * i4;            \
        _Pragma("unroll") for (int nn = 0; nn < 2; ++nn) {                        \
            int n = 2 * npair + nn;                                               \
            half4 h;                                                              \
            h[0] = (_Float16)(nn ? vb[PR][0].y : vb[PR][0].x);                    \
            h[1] = (_Float16)(nn ? vb[PR][1].y : vb[PR][1].x);                    \
            h[2] = (_Float16)(nn ? vb[PR][2].y : vb[PR][2].x);                    \
            h[3] = (_Float16)(nn ? vb[PR][3].y : vb[PR][3].x);                    \
            *(half4*)(&X[SWZ16(kk, n, i4 * 4)]) = h;                              \
        } } while (0)

    LOADP(0, 0); LOADP(1, 1); LOADP(2, 2);   // 12 loads in flight
    WRITEP(0, 0); LOADP(3, 0);
    WRITEP(1, 1); LOADP(4, 1);
    WRITEP(2, 2); LOADP(5, 2);
    WRITEP(3, 0); WRITEP(4, 1); WRITEP(5, 2);
    __syncthreads();     // the ONLY barrier: X is read-only from here on

    // ---- MFMA: d = W'@x_hi, W split hi+lo (2 passes), K fully resident ----
    f32x4 acc[3][2][2];  // [k][cf][nf]
    const f32x4 zero = {0.f, 0.f, 0.f, 0.f};
#pragma unroll
    for (int k = 0; k < 3; ++k)
#pragma unroll
        for (int cf = 0; cf < 2; ++cf)
#pragma unroll
            for (int nf = 0; nf < 2; ++nf) acc[k][cf][nf] = zero;

#pragma unroll
    for (int s = 0; s < 8; ++s) {
        const int P = s & 1;
        // B-frags for this slice (LDS)
        half8 bh[3][2];
#pragma unroll
        for (int k = 0; k < 3; ++k)
#pragma unroll
            for (int nf = 0; nf < 2; ++nf)
                bh[k][nf] = *(const half8*)(&X[SWZ16(k, (nf << 4) | t16, (s << 5) + (g << 3))]);
        // prefetch next slice's hi frags (cover = this slice's hi+lo passes)
        if (s < 7)
#pragma unroll
            for (int cf = 0; cf < 2; ++cf)
                ah[P ^ 1][cf] = *(const half8*)(WfH + WOFF(cf, s + 1));
        // hi pass
#pragma unroll
        for (int k = 0; k < 3; ++k)
#pragma unroll
            for (int cf = 0; cf < 2; ++cf)
#pragma unroll
                for (int nf = 0; nf < 2; ++nf)
                    acc[k][cf][nf] = __builtin_amdgcn_mfma_f32_16x16x32_f16(ah[P][cf], bh[k][nf], acc[k][cf][nf], 0, 0, 0);
        // lo pass
#pragma unroll
        for (int k = 0; k < 3; ++k)
#pragma unroll
            for (int cf = 0; cf < 2; ++cf)
#pragma unroll
                for (int nf = 0; nf < 2; ++nf)
                    acc[k][cf][nf] = __builtin_amdgcn_mfma_f32_16x16x32_f16(al[cf], bh[k][nf], acc[k][cf][nf], 0, 0, 0);
        // al now dead: issue next slice's lo frags (cover = next slice's hi pass)
        if (s < 7)
#pragma unroll
            for (int cf = 0; cf < 2; ++cf)
                al[cf] = *(const half8*)(WfL + WOFF(cf, s + 1));
    }

    // ---- epilogue: dp from LDS x, pack keys, merge both n-halves per 32-n window ----
#pragma unroll
    for (int cf = 0; cf < 2; ++cf) {
        half4 xrA[3], xrB[3];
        const int ci = (wid << 5) + (cf << 4) + (g << 2);
#pragma unroll
        for (int k = 0; k < 3; ++k) {
            xrA[k] = *(const half4*)(&X[SWZ16(k, t16,      ci)]);
            xrB[k] = *(const half4*)(&X[SWZ16(k, 16 | t16, ci)]);
        }
#pragma unroll
        for (int r = 0; r < 4; ++r) {
            float dpA = 0.f, dpB = 0.f;
#pragma unroll
            for (int k = 0; k < 3; ++k) {
                dpA += (float)xrA[k][r] * acc[k][cf][0][r];
                dpB += (float)xrB[k][r] * acc[k][cf][1][r];
            }
            dpA *= 0.0625f; dpB *= 0.0625f;
            unsigned uA = __float_as_uint(dpA);
            unsigned keyA = (uA & 0x80000000u) ? ~uA : (uA | 0x80000000u);
            unsigned uB = __float_as_uint(dpB);
            unsigned keyB = (uB & 0x80000000u) ? ~uB : (uB | 0x80000000u);
            int nA = n0 + t16, nB = n0 + 16 + t16;
            u64 A1 = ((u64)keyA << 32) | (unsigned)(~nA);
            u64 A2 = 0;
            u64 B1 = ((u64)keyB << 32) | (unsigned)(~nB);
            t2m(A1, A2, B1, 0);
#pragma unroll
            for (int m = 1; m <= 8; m <<= 1) {
                u64 C1 = shfl_xor_u64(A1, m);
                u64 C2 = shfl_xor_u64(A2, m);
                t2m(A1, A2, C1, C2);
            }
            if (t16 == 0) {
                int c = ci + r;
                btop[(size_t)((b << 8) + c) * 128 + nb] = make_ulonglong2(A1, A2);
            }
        }
    }
}

// ---------- phase2: merge 128 windows, certify or exact-recompute, gather ----------
__global__ void phase2(const float* __restrict__ x, const float* __restrict__ W,
                       const ulonglong2* __restrict__ btop, float* __restrict__ out)
{
    const int bc = blockIdx.x;
    const int b = bc >> 8, c = bc & 255;
    const int lane = threadIdx.x;

    u64 A1 = 0, A2 = 0;
    u64 e1[2];
#pragma unroll
    for (int t = 0; t < 2; ++t) {
        ulonglong2 e = btop[(size_t)bc * 128 + t * 64 + lane];
        e1[t] = e.x;
        t2m(A1, A2, e.x, e.y);
    }
#pragma unroll
    for (int m = 1; m <= 32; m <<= 1) {
        u64 B1 = shfl_xor_u64(A1, m);
        u64 B2 = shfl_xor_u64(A2, m);
        t2m(A1, A2, B1, B2);
    }
    float v1 = unkey((unsigned)(A1 >> 32));
    float v2 = unkey((unsigned)(A2 >> 32));
    int winner = (int)(~(unsigned)A1) & (N_ - 1);

    if (!(v1 - v2 > TAU)) {
        float bv = -3.4e38f; int bi = 0x7fffffff;
#pragma unroll
        for (int t = 0; t < 2; ++t) {
            bool flag = unkey((unsigned)(e1[t] >> 32)) >= v1 - TAU;
            unsigned long long mask = __ballot(flag);
            while (mask) {
                int src = __builtin_ctzll(mask);
                mask &= mask - 1;
                int win = t * 64 + src;       // 32-n window
                for (int ch = 0; ch < 4; ++ch) {
                    int nbase = win * 32 + ch * 8;
                    float accv[8];
#pragma unroll
                    for (int m2 = 0; m2 < 8; ++m2) accv[m2] = 0.f;
                    float xc[3][8];
#pragma unroll
                    for (int k = 0; k < 3; ++k) {
                        const float* p = x + (((size_t)bc * 3 + k) << 12) + nbase;
#pragma unroll
                        for (int m2 = 0; m2 < 8; ++m2) xc[k][m2] = p[m2];
                    }
                    for (int q = 0; q < 4; ++q) {
                        int i = lane + (q << 6);
                        float wq = W[c * C_ + i];
#pragma unroll
                        for (int k = 0; k < 3; ++k) {
                            const float* p = x + ((((size_t)b * C_ + i) * 3 + k) << 12) + nbase;
#pragma unroll
                            for (int m2 = 0; m2 < 8; ++m2)
                                accv[m2] += wq * p[m2] * xc[k][m2];
                        }
                    }
#pragma unroll
                    for (int m2 = 0; m2 < 8; ++m2) {
#pragma unroll
                        for (int mm = 1; mm <= 32; mm <<= 1)
                            accv[m2] += __shfl_xor(accv[m2], mm);
                        int n = nbase + m2;
                        if (accv[m2] > bv || (accv[m2] == bv && n < bi)) { bv = accv[m2]; bi = n; }
                    }
                }
            }
        }
        winner = bi;
    }

    if (lane < 3)
        out[bc * 3 + lane] = x[(((size_t)bc * 3 + lane) << 12) + winner];
}

extern "C" void kernel_launch(void* const* d_in, const int* in_sizes, int n_in,
                              void* d_out, int out_size, void* d_ws, size_t ws_size,
                              hipStream_t stream) {
    const float* x = (const float*)d_in[0];
    const float* W = (const float*)d_in[1];
    float* out = (float*)d_out;

    _Float16*   WfH  = (_Float16*)d_ws;                      // 128 KB
    _Float16*   WfL  = (_Float16*)((char*)d_ws + 131072);    // 128 KB
    ulonglong2* btop = (ulonglong2*)((char*)d_ws + 262144);  // 8 MB: [bc][128] (K1,K2)

    prep_w<<<32, 256, 0, stream>>>(W, WfH, WfL);
    vn_main<<<B_ * 128, 512, 0, stream>>>(x, WfH, WfL, btop);
    phase2<<<B_ * C_, 64, 0, stream>>>(x, W, btop, out);
}